// Round 1
// baseline (361.650 us; speedup 1.0000x reference)
//
#include <hip/hip_runtime.h>

// BERT-CRF NLL: feats = X @ W^T + b  (B*T=65536 x H=768 x L=12), then CRF
// forward recursion (T=128, logsumexp over L=12) and gold path score,
// output = mean_b(forward_b - gold_b).
//
// Kernel A (feats): memory-bound on reading X (201 MB f32). W in LDS,
//   16-lane groups x 2 rows each, float4 loads, butterfly reduce.
// Kernel B (crf): 16 lanes per batch (4 batches/wave). E=exp(trans) in regs
//   -> 1 exp + 1 log per step per lane. Feats row staged in padded LDS.
// Kernel C: mean over 512 per-batch scores.

#define Bsz 512
#define Tt  128
#define Hh  768
#define Ll  12
#define START_TAG 9
#define NEGV -10000.0f

// ---------------------------------------------------------------- kernel A
// grid 2048 x 256 threads; each block: 16 groups x 2 rows = 32 rows.
__global__ __launch_bounds__(256) void feats_kernel(
    const float* __restrict__ X, const float* __restrict__ W,
    const float* __restrict__ bias, float* __restrict__ feats)
{
  __shared__ float sW[Ll * Hh];   // 36 KB
  __shared__ float sB[Ll];
  const int tid = threadIdx.x;

  for (int i = tid; i < Ll * Hh / 4; i += 256)
    reinterpret_cast<float4*>(sW)[i] = reinterpret_cast<const float4*>(W)[i];
  if (tid < Ll) sB[tid] = bias[tid];
  __syncthreads();

  float sbr[Ll];
#pragma unroll
  for (int l = 0; l < Ll; ++l) sbr[l] = sB[l];

  const int gidx = tid >> 4;      // 0..15: group within block
  const int j    = tid & 15;      // lane within group
  const int row0 = blockIdx.x * 32 + gidx * 2;
  const int row1 = row0 + 1;

  const float* x0 = X + (size_t)row0 * Hh;
  const float* x1 = X + (size_t)row1 * Hh;

  float acc0[Ll], acc1[Ll];
#pragma unroll
  for (int l = 0; l < Ll; ++l) { acc0[l] = 0.f; acc1[l] = 0.f; }

#pragma unroll
  for (int it = 0; it < Hh / 64; ++it) {         // 12 iters
    const int h = 4 * j + 64 * it;               // 16 lanes cover 64 floats
    const float4 xa = *reinterpret_cast<const float4*>(x0 + h);
    const float4 xb = *reinterpret_cast<const float4*>(x1 + h);
#pragma unroll
    for (int l = 0; l < Ll; ++l) {
      const float4 wv = *reinterpret_cast<const float4*>(sW + l * Hh + h);
      acc0[l] += xa.x * wv.x + xa.y * wv.y + xa.z * wv.z + xa.w * wv.w;
      acc1[l] += xb.x * wv.x + xb.y * wv.y + xb.z * wv.z + xb.w * wv.w;
    }
  }

  // 16-lane butterfly reduce (every lane ends with the total)
#pragma unroll
  for (int l = 0; l < Ll; ++l) {
#pragma unroll
    for (int d = 1; d < 16; d <<= 1) {
      acc0[l] += __shfl_xor(acc0[l], d, 16);
      acc1[l] += __shfl_xor(acc1[l], d, 16);
    }
  }

  if (j == 0) {
    float* o0 = feats + (size_t)row0 * Ll;
    float* o1 = feats + (size_t)row1 * Ll;
    *reinterpret_cast<float4*>(o0 + 0) = make_float4(acc0[0]+sbr[0], acc0[1]+sbr[1], acc0[2]+sbr[2],  acc0[3]+sbr[3]);
    *reinterpret_cast<float4*>(o0 + 4) = make_float4(acc0[4]+sbr[4], acc0[5]+sbr[5], acc0[6]+sbr[6],  acc0[7]+sbr[7]);
    *reinterpret_cast<float4*>(o0 + 8) = make_float4(acc0[8]+sbr[8], acc0[9]+sbr[9], acc0[10]+sbr[10],acc0[11]+sbr[11]);
    *reinterpret_cast<float4*>(o1 + 0) = make_float4(acc1[0]+sbr[0], acc1[1]+sbr[1], acc1[2]+sbr[2],  acc1[3]+sbr[3]);
    *reinterpret_cast<float4*>(o1 + 4) = make_float4(acc1[4]+sbr[4], acc1[5]+sbr[5], acc1[6]+sbr[6],  acc1[7]+sbr[7]);
    *reinterpret_cast<float4*>(o1 + 8) = make_float4(acc1[8]+sbr[8], acc1[9]+sbr[9], acc1[10]+sbr[10],acc1[11]+sbr[11]);
  }
}

// ---------------------------------------------------------------- kernel B
// grid 128 x 64 threads; block handles 4 batches (one per 16-lane group).
#define FSTRIDE 1544   // 128*12 + 8 pad (breaks 4-way cross-group bank alias)
__global__ __launch_bounds__(64) void crf_kernel(
    const float* __restrict__ feats, const float* __restrict__ trans,
    const int* __restrict__ labels, float* __restrict__ bscores)
{
  __shared__ float sf[4 * FSTRIDE];
  __shared__ float st[Ll * Ll];
  const int tid = threadIdx.x;
  const int g   = tid >> 4;   // batch-group 0..3
  const int j   = tid & 15;   // lane within group (states 0..11 active)
  const int batch0 = blockIdx.x * 4;

  for (int i = tid; i < Ll * Ll; i += 64) st[i] = trans[i];
  for (int g2 = 0; g2 < 4; ++g2) {
    const float4* src = reinterpret_cast<const float4*>(
        feats + (size_t)(batch0 + g2) * (Tt * Ll));
    float4* dst = reinterpret_cast<float4*>(sf + g2 * FSTRIDE);
    for (int i = tid; i < Tt * Ll / 4; i += 64) dst[i] = src[i];
  }
  __syncthreads();

  // E[l][k] = exp(trans[l][k]); exp(-10000) underflows to 0 exactly, so the
  // shared-shift logsumexp below matches the per-row-max reference to f32.
  float E[Ll];
#pragma unroll
  for (int k = 0; k < Ll; ++k) E[k] = 0.f;
  if (j < Ll) {
#pragma unroll
    for (int k = 0; k < Ll; ++k) E[k] = __expf(st[j * Ll + k]);
  }

  const float* fme = sf + g * FSTRIDE;
  float alpha = (j == START_TAG) ? 0.0f : NEGV;

  for (int t = 1; t < Tt; ++t) {
    float m = alpha;
#pragma unroll
    for (int d = 8; d >= 1; d >>= 1) m = fmaxf(m, __shfl_xor(m, d, 16));
    const float p = __expf(alpha - m);          // lanes >=12: ~0
    float s = 0.f;
#pragma unroll
    for (int k = 0; k < Ll; ++k) s = fmaf(E[k], __shfl(p, k, 16), s);
    const float anew = m + __logf(s) + fme[t * Ll + j];
    alpha = (j < Ll) ? anew : NEGV;
  }

  // forward score = logsumexp over states
  float m = alpha;
#pragma unroll
  for (int d = 8; d >= 1; d >>= 1) m = fmaxf(m, __shfl_xor(m, d, 16));
  float p = __expf(alpha - m);
#pragma unroll
  for (int d = 8; d >= 1; d >>= 1) p += __shfl_xor(p, d, 16);
  const float fwd = m + __logf(p);

  // gold score: sum_t trans[lab[t+1],lab[t]] + feats[t+1][lab[t+1]]
  const int* lab = labels + (size_t)(batch0 + g) * Tt;
  float gs = 0.f;
  for (int t = j; t < Tt - 1; t += 16) {
    const int pv = lab[t], nx = lab[t + 1];
    gs += st[nx * Ll + pv] + fme[(t + 1) * Ll + nx];
  }
#pragma unroll
  for (int d = 8; d >= 1; d >>= 1) gs += __shfl_xor(gs, d, 16);

  if (j == 0) bscores[batch0 + g] = fwd - gs;
}

// ---------------------------------------------------------------- kernel C
__global__ __launch_bounds__(64) void reduce_kernel(
    const float* __restrict__ bs, float* __restrict__ out)
{
  const int tid = threadIdx.x;
  float s = 0.f;
  for (int i = tid; i < Bsz; i += 64) s += bs[i];
#pragma unroll
  for (int d = 32; d >= 1; d >>= 1) s += __shfl_xor(s, d, 64);
  if (tid == 0) out[0] = s * (1.0f / Bsz);
}

// ---------------------------------------------------------------- launch
extern "C" void kernel_launch(void* const* d_in, const int* in_sizes, int n_in,
                              void* d_out, int out_size, void* d_ws, size_t ws_size,
                              hipStream_t stream) {
  const float* X     = (const float*)d_in[0];   // (512,128,768) f32
  const float* W     = (const float*)d_in[1];   // (12,768) f32
  const float* b     = (const float*)d_in[2];   // (12,) f32
  const float* trans = (const float*)d_in[3];   // (12,12) f32
  const int*   lab   = (const int*)d_in[4];     // (512,128) int
  float* out = (float*)d_out;

  float* feats   = (float*)d_ws;                          // 786432 f32 (3 MB)
  float* bscores = feats + (size_t)Bsz * Tt * Ll;         // 512 f32

  feats_kernel<<<(Bsz * Tt) / 32, 256, 0, stream>>>(X, W, b, feats);
  crf_kernel<<<Bsz / 4, 64, 0, stream>>>(feats, trans, lab, bscores);
  reduce_kernel<<<1, 64, 0, stream>>>(bscores, out);
}

// Round 3
// 337.308 us; speedup vs baseline: 1.0722x; 1.0722x over previous
//
#include <hip/hip_runtime.h>

// BERT-CRF NLL: feats = X @ W^T + b  (65536 x 768 x 12), CRF forward + gold
// score, mean over batch.
//
// R2 changes (resubmitted R3 after acquisition timeout):
//  - feats: 4 rows per 16-lane group (halves LDS read traffic vs R1).
//  - crf: max-free logsumexp. Normalize log-alpha to lane 0 (beta_0 == 0):
//      p = exp(beta); s_j = dot(E_j, p); s_0 = dot(E_0, p) (redundant per
//      lane, zero cross-lane ops); beta' = (log s_j + f_j) - (log s_0 + f_0);
//      c += log s_0 + f_0.  Removes the 4-deep shfl max tree per step.
//      exp(-10000)=0 handles the START/STOP masking exactly like the ref.

#define Bsz 512
#define Tt  128
#define Hh  768
#define Ll  12
#define START_TAG 9
#define NEGV -10000.0f

// ---------------------------------------------------------------- kernel A
// grid 1024 x 256 threads; block: 16 groups x 4 rows = 64 rows.
__global__ __launch_bounds__(256) void feats_kernel(
    const float* __restrict__ X, const float* __restrict__ W,
    const float* __restrict__ bias, float* __restrict__ feats)
{
  __shared__ float sW[Ll * Hh];   // 36 KB
  __shared__ float sB[Ll];
  const int tid = threadIdx.x;

  for (int i = tid; i < Ll * Hh / 4; i += 256)
    reinterpret_cast<float4*>(sW)[i] = reinterpret_cast<const float4*>(W)[i];
  if (tid < Ll) sB[tid] = bias[tid];
  __syncthreads();

  const int gidx = tid >> 4;      // 0..15
  const int j    = tid & 15;
  const int row0 = blockIdx.x * 64 + gidx * 4;

  const float* x0 = X + (size_t)row0 * Hh;
  const float* x1 = x0 + Hh;
  const float* x2 = x1 + Hh;
  const float* x3 = x2 + Hh;

  float acc0[Ll], acc1[Ll], acc2[Ll], acc3[Ll];
#pragma unroll
  for (int l = 0; l < Ll; ++l) { acc0[l]=0.f; acc1[l]=0.f; acc2[l]=0.f; acc3[l]=0.f; }

#pragma unroll
  for (int it = 0; it < Hh / 64; ++it) {         // 12 iters
    const int h = 4 * j + 64 * it;
    const float4 xa = *reinterpret_cast<const float4*>(x0 + h);
    const float4 xb = *reinterpret_cast<const float4*>(x1 + h);
    const float4 xc = *reinterpret_cast<const float4*>(x2 + h);
    const float4 xd = *reinterpret_cast<const float4*>(x3 + h);
#pragma unroll
    for (int l = 0; l < Ll; ++l) {
      const float4 wv = *reinterpret_cast<const float4*>(sW + l * Hh + h);
      acc0[l] += xa.x*wv.x + xa.y*wv.y + xa.z*wv.z + xa.w*wv.w;
      acc1[l] += xb.x*wv.x + xb.y*wv.y + xb.z*wv.z + xb.w*wv.w;
      acc2[l] += xc.x*wv.x + xc.y*wv.y + xc.z*wv.z + xc.w*wv.w;
      acc3[l] += xd.x*wv.x + xd.y*wv.y + xd.z*wv.z + xd.w*wv.w;
    }
  }

#pragma unroll
  for (int l = 0; l < Ll; ++l) {
#pragma unroll
    for (int d = 1; d < 16; d <<= 1) {
      acc0[l] += __shfl_xor(acc0[l], d, 16);
      acc1[l] += __shfl_xor(acc1[l], d, 16);
      acc2[l] += __shfl_xor(acc2[l], d, 16);
      acc3[l] += __shfl_xor(acc3[l], d, 16);
    }
  }

  if (j == 0) {
    float* o = feats + (size_t)row0 * Ll;
    *reinterpret_cast<float4*>(o + 0) = make_float4(acc0[0]+sB[0], acc0[1]+sB[1], acc0[2]+sB[2],  acc0[3]+sB[3]);
    *reinterpret_cast<float4*>(o + 4) = make_float4(acc0[4]+sB[4], acc0[5]+sB[5], acc0[6]+sB[6],  acc0[7]+sB[7]);
    *reinterpret_cast<float4*>(o + 8) = make_float4(acc0[8]+sB[8], acc0[9]+sB[9], acc0[10]+sB[10],acc0[11]+sB[11]);
    o += Ll;
    *reinterpret_cast<float4*>(o + 0) = make_float4(acc1[0]+sB[0], acc1[1]+sB[1], acc1[2]+sB[2],  acc1[3]+sB[3]);
    *reinterpret_cast<float4*>(o + 4) = make_float4(acc1[4]+sB[4], acc1[5]+sB[5], acc1[6]+sB[6],  acc1[7]+sB[7]);
    *reinterpret_cast<float4*>(o + 8) = make_float4(acc1[8]+sB[8], acc1[9]+sB[9], acc1[10]+sB[10],acc1[11]+sB[11]);
    o += Ll;
    *reinterpret_cast<float4*>(o + 0) = make_float4(acc2[0]+sB[0], acc2[1]+sB[1], acc2[2]+sB[2],  acc2[3]+sB[3]);
    *reinterpret_cast<float4*>(o + 4) = make_float4(acc2[4]+sB[4], acc2[5]+sB[5], acc2[6]+sB[6],  acc2[7]+sB[7]);
    *reinterpret_cast<float4*>(o + 8) = make_float4(acc2[8]+sB[8], acc2[9]+sB[9], acc2[10]+sB[10],acc2[11]+sB[11]);
    o += Ll;
    *reinterpret_cast<float4*>(o + 0) = make_float4(acc3[0]+sB[0], acc3[1]+sB[1], acc3[2]+sB[2],  acc3[3]+sB[3]);
    *reinterpret_cast<float4*>(o + 4) = make_float4(acc3[4]+sB[4], acc3[5]+sB[5], acc3[6]+sB[6],  acc3[7]+sB[7]);
    *reinterpret_cast<float4*>(o + 8) = make_float4(acc3[8]+sB[8], acc3[9]+sB[9], acc3[10]+sB[10],acc3[11]+sB[11]);
  }
}

// ---------------------------------------------------------------- kernel B
// grid 128 x 64 threads; block = 1 wave = 4 batches (16 lanes each).
#define FSTRIDE 1544   // 1536 + 8: offsets cross-group bank ranges by 8
__global__ __launch_bounds__(64) void crf_kernel(
    const float* __restrict__ feats, const float* __restrict__ trans,
    const int* __restrict__ labels, float* __restrict__ bscores)
{
  __shared__ float sf[4 * FSTRIDE];
  __shared__ float st[Ll * Ll];
  const int tid = threadIdx.x;
  const int g   = tid >> 4;
  const int j   = tid & 15;
  const int jj  = (j < Ll) ? j : (Ll - 1);   // clamp; lanes 12-15 compute junk, never read
  const int batch0 = blockIdx.x * 4;

  for (int i = tid; i < Ll * Ll; i += 64) st[i] = trans[i];
  for (int g2 = 0; g2 < 4; ++g2) {
    const float4* src = reinterpret_cast<const float4*>(
        feats + (size_t)(batch0 + g2) * (Tt * Ll));
    float4* dst = reinterpret_cast<float4*>(sf + g2 * FSTRIDE);
    for (int i = tid; i < Tt * Ll / 4; i += 64) dst[i] = src[i];
  }
  __syncthreads();

  // E[k] = exp(trans[jj][k]) (this lane's row); E0[k] = exp(trans[0][k]).
  // exp(-10000) flushes to 0 => START row / STOP col masked exactly as ref.
  float E[Ll], E0[Ll];
#pragma unroll
  for (int k = 0; k < Ll; ++k) {
    E[k]  = __expf(st[jj * Ll + k]);
    E0[k] = __expf(st[k]);
  }

  const float* fme = sf + g * FSTRIDE;
  float beta = (j == START_TAG) ? 0.0f : NEGV;   // alpha relative to running c
  float c = 0.0f;                                 // accumulated shift (all lanes)

  for (int t = 1; t < Tt; ++t) {
    const float p = __expf(beta);                 // lanes with beta=-1e4/-inf -> 0
    float ph[Ll];
#pragma unroll
    for (int k = 0; k < Ll; ++k) ph[k] = __shfl(p, k, 16);
    // two dots over the same broadcasts; 3-way split chains (depth 4)
    float sa = 0.f, sb = 0.f, sc = 0.f, za = 0.f, zb = 0.f, zc = 0.f;
#pragma unroll
    for (int k = 0; k < Ll; k += 3) {
      sa = fmaf(E[k],    ph[k],   sa);  za = fmaf(E0[k],    ph[k],   za);
      sb = fmaf(E[k+1],  ph[k+1], sb);  zb = fmaf(E0[k+1],  ph[k+1], zb);
      sc = fmaf(E[k+2],  ph[k+2], sc);  zc = fmaf(E0[k+2],  ph[k+2], zc);
    }
    const float s  = (sa + sb) + sc;
    const float s0 = (za + zb) + zc;
    const float fj = fme[t * Ll + jj];
    const float f0 = fme[t * Ll];
    const float a0 = __logf(s0) + f0;
    beta = (__logf(s) + fj) - a0;
    c += a0;
  }

  // forward = c + logsumexp_j(beta); mask lanes >= 12
  float bv = (j < Ll) ? beta : NEGV;
  float m = bv;
#pragma unroll
  for (int d = 8; d >= 1; d >>= 1) m = fmaxf(m, __shfl_xor(m, d, 16));
  float p = __expf(bv - m);
#pragma unroll
  for (int d = 8; d >= 1; d >>= 1) p += __shfl_xor(p, d, 16);
  const float fwd = c + m + __logf(p);

  // gold score
  const int* lab = labels + (size_t)(batch0 + g) * Tt;
  float gs = 0.f;
  for (int t = j; t < Tt - 1; t += 16) {
    const int pv = lab[t], nx = lab[t + 1];
    gs += st[nx * Ll + pv] + fme[(t + 1) * Ll + nx];
  }
#pragma unroll
  for (int d = 8; d >= 1; d >>= 1) gs += __shfl_xor(gs, d, 16);

  if (j == 0) bscores[batch0 + g] = fwd - gs;
}

// ---------------------------------------------------------------- kernel C
__global__ __launch_bounds__(64) void reduce_kernel(
    const float* __restrict__ bs, float* __restrict__ out)
{
  const int tid = threadIdx.x;
  float s = 0.f;
  for (int i = tid; i < Bsz; i += 64) s += bs[i];
#pragma unroll
  for (int d = 32; d >= 1; d >>= 1) s += __shfl_xor(s, d, 64);
  if (tid == 0) out[0] = s * (1.0f / Bsz);
}

// ---------------------------------------------------------------- launch
extern "C" void kernel_launch(void* const* d_in, const int* in_sizes, int n_in,
                              void* d_out, int out_size, void* d_ws, size_t ws_size,
                              hipStream_t stream) {
  const float* X     = (const float*)d_in[0];
  const float* W     = (const float*)d_in[1];
  const float* b     = (const float*)d_in[2];
  const float* trans = (const float*)d_in[3];
  const int*   lab   = (const int*)d_in[4];
  float* out = (float*)d_out;

  float* feats   = (float*)d_ws;
  float* bscores = feats + (size_t)Bsz * Tt * Ll;

  feats_kernel<<<(Bsz * Tt) / 64, 256, 0, stream>>>(X, W, b, feats);
  crf_kernel<<<Bsz / 4, 64, 0, stream>>>(feats, trans, lab, bscores);
  reduce_kernel<<<1, 64, 0, stream>>>(bscores, out);
}

// Round 4
// 334.247 us; speedup vs baseline: 1.0820x; 1.0092x over previous
//
#include <hip/hip_runtime.h>

// BERT-CRF NLL, fused: one block per batch computes feats = X[b] @ W^T + b
// into LDS (never touches HBM), then runs the CRF forward recursion and gold
// score in the same block. Small second kernel does the mean over batches.
//
// R4: fusion removes the feats global round-trip, one kernel launch, and
// hides the serial CRF tail (1 wave, ~8 us) under other blocks' HBM phase.
// CRF uses the R2 max-free logsumexp (lane-0 normalization), absmax==0.

#define Bsz 512
#define Tt  128
#define Hh  768
#define Ll  12
#define START_TAG 9
#define NEGV -10000.0f

// ---------------------------------------------------------------- fused
// grid 512 x 256. Per block: 16 groups x 16 lanes; each group computes 8
// feats rows (768-dot x 12 labels), then group 0 of wave 0 runs the
// recursion while wave 1 does the gold score.
__global__ __launch_bounds__(256) void fused_kernel(
    const float* __restrict__ X, const float* __restrict__ W,
    const float* __restrict__ bias, const float* __restrict__ trans,
    const int* __restrict__ labels, float* __restrict__ bscores)
{
  __shared__ float sW[Ll * Hh];    // 36 KB
  __shared__ float sT[Ll * Ll];
  __shared__ float sB[Ll];
  __shared__ float sF[Tt * Ll];    // 6 KB feats
  __shared__ float sFwd, sGold;

  const int tid = threadIdx.x;
  const int b   = blockIdx.x;

  for (int i = tid; i < Ll * Hh / 4; i += 256)
    reinterpret_cast<float4*>(sW)[i] = reinterpret_cast<const float4*>(W)[i];
  if (tid < Ll * Ll) sT[tid] = trans[tid];
  if (tid < Ll)      sB[tid] = bias[tid];
  __syncthreads();

  // ---- phase 1: feats into sF -------------------------------------------
  const int g = tid >> 4;          // group 0..15
  const int j = tid & 15;          // lane in group
  const int row0 = g * 8;          // 8 rows per group
  const float* xb = X + ((size_t)b * Tt + row0) * Hh;

  float acc[8][Ll];
#pragma unroll
  for (int r = 0; r < 8; ++r)
#pragma unroll
    for (int l = 0; l < Ll; ++l) acc[r][l] = 0.f;

#pragma unroll 2
  for (int it = 0; it < Hh / 64; ++it) {     // 12 iters, 16 lanes x f4 = 64
    const int h = 4 * j + 64 * it;
    float4 xv[8];
#pragma unroll
    for (int r = 0; r < 8; ++r)
      xv[r] = *reinterpret_cast<const float4*>(xb + r * Hh + h);
#pragma unroll
    for (int l = 0; l < Ll; ++l) {
      const float4 wv = *reinterpret_cast<const float4*>(sW + l * Hh + h);
#pragma unroll
      for (int r = 0; r < 8; ++r)
        acc[r][l] += xv[r].x*wv.x + xv[r].y*wv.y + xv[r].z*wv.z + xv[r].w*wv.w;
    }
  }

#pragma unroll
  for (int r = 0; r < 8; ++r)
#pragma unroll
    for (int l = 0; l < Ll; ++l)
#pragma unroll
      for (int d = 1; d < 16; d <<= 1)
        acc[r][l] += __shfl_xor(acc[r][l], d, 16);

  if (j == 0) {
#pragma unroll
    for (int r = 0; r < 8; ++r) {
      float* o = sF + (row0 + r) * Ll;
      *reinterpret_cast<float4*>(o + 0) = make_float4(acc[r][0]+sB[0], acc[r][1]+sB[1], acc[r][2]+sB[2],  acc[r][3]+sB[3]);
      *reinterpret_cast<float4*>(o + 4) = make_float4(acc[r][4]+sB[4], acc[r][5]+sB[5], acc[r][6]+sB[6],  acc[r][7]+sB[7]);
      *reinterpret_cast<float4*>(o + 8) = make_float4(acc[r][8]+sB[8], acc[r][9]+sB[9], acc[r][10]+sB[10],acc[r][11]+sB[11]);
    }
  }
  __syncthreads();

  // ---- phase 2: CRF recursion (lanes 0-15) + gold score (wave 1) --------
  if (tid < 16) {
    const int jj = (tid < Ll) ? tid : (Ll - 1);
    float E[Ll], E0[Ll];
#pragma unroll
    for (int k = 0; k < Ll; ++k) {
      E[k]  = __expf(sT[jj * Ll + k]);
      E0[k] = __expf(sT[k]);
    }
    float beta = (tid == START_TAG) ? 0.0f : NEGV;
    float c = 0.0f;
    for (int t = 1; t < Tt; ++t) {
      const float p = __expf(beta);
      float ph[Ll];
#pragma unroll
      for (int k = 0; k < Ll; ++k) ph[k] = __shfl(p, k, 16);
      float sa = 0.f, sb = 0.f, sc = 0.f, za = 0.f, zb = 0.f, zc = 0.f;
#pragma unroll
      for (int k = 0; k < Ll; k += 3) {
        sa = fmaf(E[k],   ph[k],   sa);  za = fmaf(E0[k],   ph[k],   za);
        sb = fmaf(E[k+1], ph[k+1], sb);  zb = fmaf(E0[k+1], ph[k+1], zb);
        sc = fmaf(E[k+2], ph[k+2], sc);  zc = fmaf(E0[k+2], ph[k+2], zc);
      }
      const float s  = (sa + sb) + sc;
      const float s0 = (za + zb) + zc;
      const float a0 = __logf(s0) + sF[t * Ll];
      beta = (__logf(s) + sF[t * Ll + jj]) - a0;
      c += a0;
    }
    float bv = (tid < Ll) ? beta : NEGV;
    float m = bv;
#pragma unroll
    for (int d = 8; d >= 1; d >>= 1) m = fmaxf(m, __shfl_xor(m, d, 16));
    float p = __expf(bv - m);
#pragma unroll
    for (int d = 8; d >= 1; d >>= 1) p += __shfl_xor(p, d, 16);
    if (tid == 0) sFwd = c + m + __logf(p);
  } else if (tid >= 64 && tid < 128) {
    const int lane = tid - 64;
    const int* lab = labels + (size_t)b * Tt;
    float gs = 0.f;
    for (int t = lane; t < Tt - 1; t += 64) {
      const int pv = lab[t], nx = lab[t + 1];
      gs += sT[nx * Ll + pv] + sF[(t + 1) * Ll + nx];
    }
#pragma unroll
    for (int d = 32; d >= 1; d >>= 1) gs += __shfl_xor(gs, d, 64);
    if (lane == 0) sGold = gs;
  }
  __syncthreads();

  if (tid == 0) bscores[b] = sFwd - sGold;
}

// ---------------------------------------------------------------- reduce
__global__ __launch_bounds__(64) void reduce_kernel(
    const float* __restrict__ bs, float* __restrict__ out)
{
  const int tid = threadIdx.x;
  float s = 0.f;
  for (int i = tid; i < Bsz; i += 64) s += bs[i];
#pragma unroll
  for (int d = 32; d >= 1; d >>= 1) s += __shfl_xor(s, d, 64);
  if (tid == 0) out[0] = s * (1.0f / Bsz);
}

// ---------------------------------------------------------------- launch
extern "C" void kernel_launch(void* const* d_in, const int* in_sizes, int n_in,
                              void* d_out, int out_size, void* d_ws, size_t ws_size,
                              hipStream_t stream) {
  const float* X     = (const float*)d_in[0];
  const float* W     = (const float*)d_in[1];
  const float* b     = (const float*)d_in[2];
  const float* trans = (const float*)d_in[3];
  const int*   lab   = (const int*)d_in[4];
  float* out = (float*)d_out;

  float* bscores = (float*)d_ws;

  fused_kernel<<<Bsz, 256, 0, stream>>>(X, W, b, trans, lab, bscores);
  reduce_kernel<<<1, 64, 0, stream>>>(bscores, out);
}